// Round 10
// baseline (292.277 us; speedup 1.0000x reference)
//
#include <hip/hip_runtime.h>
#include <hip/hip_fp16.h>

// ---------------------------------------------------------------------------
// 2-layer GCN. Round 10: aggregate is at its structural traffic floor
// (~8 XCDs x 12.8MB H compulsory L2-miss ~ 92MB at ~2.2 TB/s random ceiling).
// Attack dispatches + redundant traffic instead:
//  - hist_gemm1 fat kernel: hist and gemm1 are independent -> one dispatch,
//    branched on blockIdx (union'd LDS).
//  - agg_gemm: fuse gemm2 into agg1. Wave computes layer-1 row (fp32),
//    parks it in LDS (256B), all 64 lanes then do row @ W2^T from an
//    LDS-staged stride-65 W2t (conflict-free) -> writes H2 fp16 directly.
//    Deletes gemm2 dispatch + A1 roundtrip (~25MB); extra LDS/VALU fits
//    under the gather-traffic envelope.
// Dispatches: 6 (hist_gemm1, scan_alloc, scatter0, regroup, agg_gemm, agg2).
// NEVER use cooperative grid.sync on this stack (r7: ~90us/sync).
// ---------------------------------------------------------------------------

#define D 64
#define NPB 128          // nodes per bucket (dst >> 7)
#define MAXB 784         // >= ceil(100000/128) = 782
#define CHUNK 8192       // edges per partition chunk

// === fatA: blocks [0,C) = per-chunk histogram; blocks [C,C+gbg) = gemm1 ====
__global__ __launch_bounds__(256) void hist_gemm1(const int* __restrict__ dst,
                                                  int* __restrict__ counts,
                                                  int* __restrict__ cursor,
                                                  const float* __restrict__ X,
                                                  const float* __restrict__ W1,
                                                  __half* __restrict__ H,
                                                  int nE, int B, int C, int N) {
    __shared__ __align__(16) char smem[34816];   // max(hist 3.1KB, gemm 34KB)
    const int t = threadIdx.x;
    if ((int)blockIdx.x < C) {
        // ---- histogram role ----
        int* hist = (int*)smem;
        if (blockIdx.x == 0 && t == 0) *cursor = 0;   // consumed by scan_alloc
        int c = blockIdx.x;
        for (int b = t; b < B; b += 256) hist[b] = 0;
        __syncthreads();
        int e0 = c * CHUNK;
#pragma unroll
        for (int i = 0; i < CHUNK / 256; ++i) {
            int e = e0 + i * 256 + t;
            if (e < nE) atomicAdd(&hist[dst[e] >> 7], 1);
        }
        __syncthreads();
        for (int b = t; b < B; b += 256) counts[c * B + b] = hist[b];
    } else {
        // ---- gemm1 role: H(fp16) = X(fp32) @ W1^T, 64x64 tile ----
        float* xt = (float*)smem;           // [64*68]
        float* wt = xt + 64 * 68;           // [64*68]
        const int i0 = ((int)blockIdx.x - C) * 64;
#pragma unroll
        for (int r = 0; r < 16; ++r) {
            int idx = r * 256 + t;
            int j = idx >> 6, k = idx & 63;
            wt[k * 68 + j] = W1[idx];
        }
#pragma unroll
        for (int r = 0; r < 16; ++r) {
            int idx = r * 256 + t;
            int i = idx >> 6, k = idx & 63;
            float v = 0.0f;
            if (i0 + i < N) v = X[(size_t)(i0 + i) * D + k];
            xt[k * 68 + i] = v;
        }
        __syncthreads();
        const int tn = (t & 15) * 4;
        const int tc = (t >> 4) * 4;
        float acc[4][4] = {};
#pragma unroll 8
        for (int k = 0; k < 64; ++k) {
            const float4 xa = *(const float4*)(xt + k * 68 + tn);
            const float4 wb = *(const float4*)(wt + k * 68 + tc);
            acc[0][0] += xa.x * wb.x; acc[0][1] += xa.x * wb.y; acc[0][2] += xa.x * wb.z; acc[0][3] += xa.x * wb.w;
            acc[1][0] += xa.y * wb.x; acc[1][1] += xa.y * wb.y; acc[1][2] += xa.y * wb.z; acc[1][3] += xa.y * wb.w;
            acc[2][0] += xa.z * wb.x; acc[2][1] += xa.z * wb.y; acc[2][2] += xa.z * wb.z; acc[2][3] += xa.z * wb.w;
            acc[3][0] += xa.w * wb.x; acc[3][1] += xa.w * wb.y; acc[3][2] += xa.w * wb.z; acc[3][3] += xa.w * wb.w;
        }
#pragma unroll
        for (int a = 0; a < 4; ++a) {
            int i = i0 + tn + a;
            if (i < N) {
                union { __half2 h2[2]; uint2 u2; } pk;
                pk.h2[0].x = __float2half_rn(acc[a][0]);
                pk.h2[0].y = __float2half_rn(acc[a][1]);
                pk.h2[1].x = __float2half_rn(acc[a][2]);
                pk.h2[1].y = __float2half_rn(acc[a][3]);
                *(uint2*)(&H[(size_t)i * D + tc]) = pk.u2;
            }
        }
    }
}

// --- S1: per-bucket chunk scan (in place) + region alloc via global cursor -
__global__ __launch_bounds__(256) void scan_alloc(int* __restrict__ counts,
                                                  int* __restrict__ btot,
                                                  int* __restrict__ bbase,
                                                  int* __restrict__ cursor,
                                                  int B, int C) {
    int b = blockIdx.x * 4 + (threadIdx.x >> 6);
    if (b >= B) return;
    int lane = threadIdx.x & 63;
    int running = 0;
    for (int c0 = 0; c0 < C; c0 += 64) {
        int c = c0 + lane;
        int v = (c < C) ? counts[c * B + b] : 0;
        int x = v;
#pragma unroll
        for (int s = 1; s < 64; s <<= 1) {
            int u = __shfl_up(x, s);
            if (lane >= s) x += u;
        }
        if (c < C) counts[c * B + b] = running + x - v;
        running += __shfl(x, 63);
    }
    if (lane == 0) {
        int base = atomicAdd(cursor, running);   // order-free region alloc
        bbase[b] = base;
        btot[b]  = running;
    }
}

// --- A3: scatter 4B entries (src | dloc<<17) via LDS cursors ---------------
__global__ __launch_bounds__(256) void scatter0_kernel(const int* __restrict__ src,
                                                       const int* __restrict__ dst,
                                                       const int* __restrict__ base,
                                                       const int* __restrict__ bbase,
                                                       int* __restrict__ entries0,
                                                       int nE, int B) {
    __shared__ int cur[MAXB];
    int c = blockIdx.x;
    for (int b = threadIdx.x; b < B; b += 256) cur[b] = base[c * B + b] + bbase[b];
    __syncthreads();
    int e0 = c * CHUNK;
#pragma unroll
    for (int i = 0; i < CHUNK / 256; ++i) {
        int e = e0 + i * 256 + threadIdx.x;
        if (e < nE) {
            int s = src[e], d = dst[e];
            int pos = atomicAdd(&cur[d >> 7], 1);
            entries0[pos] = s | ((d & (NPB - 1)) << 17);
        }
    }
}

// --- A4: merged regroup: count+scan -> off/deg/dinv, node-sorted src -------
__global__ __launch_bounds__(256) void regroup_kernel(const int* __restrict__ entries0,
                                                      const int* __restrict__ bbase,
                                                      const int* __restrict__ btot,
                                                      int* __restrict__ off,
                                                      int* __restrict__ deg,
                                                      float* __restrict__ dinv,
                                                      int* __restrict__ entries1, int N) {
    __shared__ int cnt[NPB];
    __shared__ int scn[NPB];
    __shared__ int cur[NPB];
    int b = blockIdx.x;
    int t = threadIdx.x;
    if (t < NPB) cnt[t] = 0;
    __syncthreads();
    int s0 = bbase[b], s1 = s0 + btot[b];
    for (int p = s0 + t; p < s1; p += 256)
        atomicAdd(&cnt[(entries0[p] >> 17) & (NPB - 1)], 1);
    __syncthreads();
    if (t < NPB) scn[t] = cnt[t];
    __syncthreads();
    for (int s = 1; s < NPB; s <<= 1) {
        int u = 0;
        if (t < NPB && t >= s) u = scn[t - s];
        __syncthreads();
        if (t < NPB) scn[t] += u;
        __syncthreads();
    }
    if (t < NPB) {
        int node = b * NPB + t;
        int c = cnt[t];
        int o = s0 + scn[t] - c;
        cur[t] = o;
        if (node < N) {
            off[node]  = o;
            deg[node]  = c;
            dinv[node] = rsqrtf((float)c + 1.0f);
        }
    }
    __syncthreads();
    for (int p = s0 + t; p < s1; p += 256) {
        int e = entries0[p];
        int pos = atomicAdd(&cur[(e >> 17) & (NPB - 1)], 1);
        entries1[pos] = e & 0x1FFFF;
    }
}

// === agg_gemm: layer-1 aggregate fused with gemm2 ==========================
// Wave computes A1 row (fp32) exactly as aggregate3, parks it in LDS, then
// all 64 lanes compute H2[node][lane] = sum_k row[k] * W2[lane][k] from a
// stride-65 LDS W2^T (conflict-free) and store fp16.
__global__ __launch_bounds__(256) void agg_gemm(const int* __restrict__ csr,
                                                const int* __restrict__ off,
                                                const int* __restrict__ deg,
                                                const float* __restrict__ dinv,
                                                const __half* __restrict__ H,
                                                const float* __restrict__ b1,
                                                const float* __restrict__ W2,
                                                __half* __restrict__ H2out, int N) {
    __shared__ float w2t[64 * 65];   // w2t[k*65+j] = W2[j*64+k]
    __shared__ float rows[4][64];
    const int t = threadIdx.x;
    // stage W2 transposed (stride 65 -> write banks (k+j)%32, read 2-way free)
#pragma unroll
    for (int r = 0; r < 16; ++r) {
        int idx = r * 256 + t;       // idx = j*64 + k
        int j = idx >> 6, k = idx & 63;
        w2t[k * 65 + j] = W2[idx];
    }
    __syncthreads();

    int node = blockIdx.x * 4 + (t >> 6);
    int lane = t & 63;
    int w = t >> 6;
    int p2 = lane & 31;
    int h  = lane >> 5;
    const __half2* H2 = (const __half2*)H;

    if (node < N) {
        float dd = dinv[node];
        float2 acc = make_float2(0.0f, 0.0f);
        int beg = off[node];
        int end = beg + deg[node];
        int p = beg;
        for (; p + 8 <= end; p += 8) {
            int s0v = csr[p + 0 + h], s1v = csr[p + 2 + h];
            int s2v = csr[p + 4 + h], s3v = csr[p + 6 + h];
            __half2 g0 = H2[(size_t)s0v * 32 + p2];
            __half2 g1 = H2[(size_t)s1v * 32 + p2];
            __half2 g2 = H2[(size_t)s2v * 32 + p2];
            __half2 g3 = H2[(size_t)s3v * 32 + p2];
            float c0 = dinv[s0v] * dd, c1 = dinv[s1v] * dd;
            float c2 = dinv[s2v] * dd, c3 = dinv[s3v] * dd;
            float2 f0 = __half22float2(g0), f1 = __half22float2(g1);
            float2 f2 = __half22float2(g2), f3 = __half22float2(g3);
            acc.x += f0.x * c0; acc.y += f0.y * c0;
            acc.x += f1.x * c1; acc.y += f1.y * c1;
            acc.x += f2.x * c2; acc.y += f2.y * c2;
            acc.x += f3.x * c3; acc.y += f3.y * c3;
        }
        for (; p + 2 <= end; p += 2) {
            int s0v = csr[p + h];
            __half2 g0 = H2[(size_t)s0v * 32 + p2];
            float c0 = dinv[s0v] * dd;
            float2 f0 = __half22float2(g0);
            acc.x += f0.x * c0; acc.y += f0.y * c0;
        }
        if (p < end && h == 0) {
            int s0v = csr[p];
            __half2 g0 = H2[(size_t)s0v * 32 + p2];
            float c0 = dinv[s0v] * dd;
            float2 f0 = __half22float2(g0);
            acc.x += f0.x * c0; acc.y += f0.y * c0;
        }
        acc.x += __shfl_xor(acc.x, 32);
        acc.y += __shfl_xor(acc.y, 32);
        if (h == 0) {
            float s = dd * dd;
            float2 hs = __half22float2(H2[(size_t)node * 32 + p2]);
            float2 bv = ((const float2*)b1)[p2];
            rows[w][2 * p2]     = acc.x + bv.x + hs.x * s;
            rows[w][2 * p2 + 1] = acc.y + bv.y + hs.y * s;
        }
    }
    __syncthreads();    // rows visible to whole block (cheap; also orders LDS)

    if (node < N) {
        float o = 0.0f;
        const float* rw = rows[w];
#pragma unroll 8
        for (int k = 0; k < 64; ++k)
            o += rw[k] * w2t[k * 65 + lane];   // rw[k]: broadcast; w2t: 2-way free
        H2out[(size_t)node * D + lane] = __float2half_rn(o);
    }
}

// --- aggregate3: one wave per node, dual-edge half2, 4B src entries --------
__global__ __launch_bounds__(256) void aggregate3(const int* __restrict__ csr,
                                                  const int* __restrict__ off,
                                                  const int* __restrict__ deg,
                                                  const float* __restrict__ dinv,
                                                  const __half* __restrict__ H,
                                                  const float* __restrict__ bias,
                                                  float* __restrict__ out, int N) {
    int node = blockIdx.x * 4 + (threadIdx.x >> 6);
    if (node >= N) return;
    int lane = threadIdx.x & 63;
    int p2 = lane & 31;
    int h  = lane >> 5;
    const __half2* H2 = (const __half2*)H;
    float dd = dinv[node];
    float2 acc = make_float2(0.0f, 0.0f);
    int beg = off[node];
    int end = beg + deg[node];
    int p = beg;
    for (; p + 8 <= end; p += 8) {
        int s0v = csr[p + 0 + h], s1v = csr[p + 2 + h];
        int s2v = csr[p + 4 + h], s3v = csr[p + 6 + h];
        __half2 g0 = H2[(size_t)s0v * 32 + p2];
        __half2 g1 = H2[(size_t)s1v * 32 + p2];
        __half2 g2 = H2[(size_t)s2v * 32 + p2];
        __half2 g3 = H2[(size_t)s3v * 32 + p2];
        float c0 = dinv[s0v] * dd, c1 = dinv[s1v] * dd;
        float c2 = dinv[s2v] * dd, c3 = dinv[s3v] * dd;
        float2 f0 = __half22float2(g0), f1 = __half22float2(g1);
        float2 f2 = __half22float2(g2), f3 = __half22float2(g3);
        acc.x += f0.x * c0; acc.y += f0.y * c0;
        acc.x += f1.x * c1; acc.y += f1.y * c1;
        acc.x += f2.x * c2; acc.y += f2.y * c2;
        acc.x += f3.x * c3; acc.y += f3.y * c3;
    }
    for (; p + 2 <= end; p += 2) {
        int s0v = csr[p + h];
        __half2 g0 = H2[(size_t)s0v * 32 + p2];
        float c0 = dinv[s0v] * dd;
        float2 f0 = __half22float2(g0);
        acc.x += f0.x * c0; acc.y += f0.y * c0;
    }
    if (p < end && h == 0) {
        int s0v = csr[p];
        __half2 g0 = H2[(size_t)s0v * 32 + p2];
        float c0 = dinv[s0v] * dd;
        float2 f0 = __half22float2(g0);
        acc.x += f0.x * c0; acc.y += f0.y * c0;
    }
    acc.x += __shfl_xor(acc.x, 32);
    acc.y += __shfl_xor(acc.y, 32);
    if (h == 0) {
        float s = dd * dd;
        float2 hs = __half22float2(H2[(size_t)node * 32 + p2]);
        float2 bv = ((const float2*)bias)[p2];
        float2 o;
        o.x = acc.x + bv.x + hs.x * s;
        o.y = acc.y + bv.y + hs.y * s;
        ((float2*)(out + (size_t)node * D))[p2] = o;
    }
}

// --- standalone hist + gemm (middle fallback path) -------------------------
__global__ __launch_bounds__(256) void hist_kernel(const int* __restrict__ dst,
                                                   int* __restrict__ counts,
                                                   int* __restrict__ cursor,
                                                   int nE, int B) {
    __shared__ int hist[MAXB];
    if (blockIdx.x == 0 && threadIdx.x == 0) *cursor = 0;
    int c = blockIdx.x;
    for (int b = threadIdx.x; b < B; b += 256) hist[b] = 0;
    __syncthreads();
    int e0 = c * CHUNK;
#pragma unroll
    for (int i = 0; i < CHUNK / 256; ++i) {
        int e = e0 + i * 256 + threadIdx.x;
        if (e < nE) atomicAdd(&hist[dst[e] >> 7], 1);
    }
    __syncthreads();
    for (int b = threadIdx.x; b < B; b += 256) counts[c * B + b] = hist[b];
}

template <typename InT>
__global__ __launch_bounds__(256) void gemm_xwt_h(const InT* __restrict__ X,
                                                  const float* __restrict__ W,
                                                  __half* __restrict__ H, int N) {
    __shared__ float xt[64 * 68];
    __shared__ float wt[64 * 68];
    const int t = threadIdx.x;
    const int i0 = blockIdx.x * 64;
#pragma unroll
    for (int r = 0; r < 16; ++r) {
        int idx = r * 256 + t;
        int j = idx >> 6, k = idx & 63;
        wt[k * 68 + j] = W[idx];
    }
#pragma unroll
    for (int r = 0; r < 16; ++r) {
        int idx = r * 256 + t;
        int i = idx >> 6, k = idx & 63;
        float v = 0.0f;
        if (i0 + i < N) {
            if constexpr (sizeof(InT) == 2)
                v = __half2float(((const __half*)X)[(size_t)(i0 + i) * D + k]);
            else
                v = ((const float*)X)[(size_t)(i0 + i) * D + k];
        }
        xt[k * 68 + i] = v;
    }
    __syncthreads();
    const int tn = (t & 15) * 4;
    const int tc = (t >> 4) * 4;
    float acc[4][4] = {};
#pragma unroll 8
    for (int k = 0; k < 64; ++k) {
        const float4 xa = *(const float4*)(xt + k * 68 + tn);
        const float4 wb = *(const float4*)(wt + k * 68 + tc);
        acc[0][0] += xa.x * wb.x; acc[0][1] += xa.x * wb.y; acc[0][2] += xa.x * wb.z; acc[0][3] += xa.x * wb.w;
        acc[1][0] += xa.y * wb.x; acc[1][1] += xa.y * wb.y; acc[1][2] += xa.y * wb.z; acc[1][3] += xa.y * wb.w;
        acc[2][0] += xa.z * wb.x; acc[2][1] += xa.z * wb.y; acc[2][2] += xa.z * wb.z; acc[2][3] += xa.z * wb.w;
        acc[3][0] += xa.w * wb.x; acc[3][1] += xa.w * wb.y; acc[3][2] += xa.w * wb.z; acc[3][3] += xa.w * wb.w;
    }
#pragma unroll
    for (int a = 0; a < 4; ++a) {
        int i = i0 + tn + a;
        if (i < N) {
            union { __half2 h2[2]; uint2 u2; } pk;
            pk.h2[0].x = __float2half_rn(acc[a][0]);
            pk.h2[0].y = __float2half_rn(acc[a][1]);
            pk.h2[1].x = __float2half_rn(acc[a][2]);
            pk.h2[1].y = __float2half_rn(acc[a][3]);
            *(uint2*)(&H[(size_t)i * D + tc]) = pk.u2;
        }
    }
}

// --- ultimate fallback (round-1 fp32 atomic path) kernels ------------------
__global__ __launch_bounds__(256) void deg_kernel(const int* __restrict__ dst,
                                                  int* __restrict__ deg, int nE) {
    int e = blockIdx.x * 256 + threadIdx.x;
    if (e < nE) atomicAdd(&deg[dst[e]], 1);
}

__global__ __launch_bounds__(256) void dinv_kernel(const int* __restrict__ deg,
                                                   float* __restrict__ dinv, int N) {
    int i = blockIdx.x * 256 + threadIdx.x;
    if (i < N) dinv[i] = rsqrtf((float)deg[i] + 1.0f);
}

__global__ __launch_bounds__(256) void gemm_xwt(const float* __restrict__ X,
                                                const float* __restrict__ W,
                                                float* __restrict__ H, int N) {
    __shared__ float xt[64 * 68];
    __shared__ float wt[64 * 68];
    const int t = threadIdx.x;
    const int i0 = blockIdx.x * 64;
#pragma unroll
    for (int r = 0; r < 16; ++r) {
        int idx = r * 256 + t;
        int j = idx >> 6, k = idx & 63;
        wt[k * 68 + j] = W[idx];
    }
#pragma unroll
    for (int r = 0; r < 16; ++r) {
        int idx = r * 256 + t;
        int i = idx >> 6, k = idx & 63;
        float v = 0.0f;
        if (i0 + i < N) v = X[(size_t)(i0 + i) * D + k];
        xt[k * 68 + i] = v;
    }
    __syncthreads();
    const int tn = (t & 15) * 4;
    const int tc = (t >> 4) * 4;
    float acc[4][4] = {};
#pragma unroll 8
    for (int k = 0; k < 64; ++k) {
        const float4 xa = *(const float4*)(xt + k * 68 + tn);
        const float4 wb = *(const float4*)(wt + k * 68 + tc);
        acc[0][0] += xa.x * wb.x; acc[0][1] += xa.x * wb.y; acc[0][2] += xa.x * wb.z; acc[0][3] += xa.x * wb.w;
        acc[1][0] += xa.y * wb.x; acc[1][1] += xa.y * wb.y; acc[1][2] += xa.y * wb.z; acc[1][3] += xa.y * wb.w;
        acc[2][0] += xa.z * wb.x; acc[2][1] += xa.z * wb.y; acc[2][2] += xa.z * wb.z; acc[2][3] += xa.z * wb.w;
        acc[3][0] += xa.w * wb.x; acc[3][1] += xa.w * wb.y; acc[3][2] += xa.w * wb.z; acc[3][3] += xa.w * wb.w;
    }
#pragma unroll
    for (int a = 0; a < 4; ++a) {
        int i = i0 + tn + a;
        if (i < N) {
            float4 o = make_float4(acc[a][0], acc[a][1], acc[a][2], acc[a][3]);
            *(float4*)(H + (size_t)i * D + tc) = o;
        }
    }
}

__global__ __launch_bounds__(256) void init_out(const float* __restrict__ H,
                                                const float* __restrict__ dinv,
                                                const float* __restrict__ b,
                                                float* __restrict__ out, int N) {
    int idx4 = blockIdx.x * 256 + threadIdx.x;
    if (idx4 >= N * 16) return;
    int i = idx4 >> 4;
    int jc = idx4 & 15;
    float di = dinv[i];
    float s = di * di;
    float4 h4 = ((const float4*)H)[idx4];
    float4 b4 = ((const float4*)b)[jc];
    ((float4*)out)[idx4] = make_float4(b4.x + h4.x * s, b4.y + h4.y * s,
                                       b4.z + h4.z * s, b4.w + h4.w * s);
}

__global__ __launch_bounds__(256) void edge_scatter(const int* __restrict__ src,
                                                    const int* __restrict__ dst,
                                                    const float* __restrict__ dinv,
                                                    const float* __restrict__ H,
                                                    float* __restrict__ out, int nE) {
    int tid = blockIdx.x * 256 + threadIdx.x;
    int e = tid >> 4;
    if (e >= nE) return;
    int l = tid & 15;
    int s = src[e];
    int d = dst[e];
    float c = dinv[s] * dinv[d];
    float4 v = ((const float4*)H)[s * 16 + l];
    float* o = out + (size_t)d * D + l * 4;
    unsafeAtomicAdd(o + 0, v.x * c);
    unsafeAtomicAdd(o + 1, v.y * c);
    unsafeAtomicAdd(o + 2, v.z * c);
    unsafeAtomicAdd(o + 3, v.w * c);
}

static inline size_t align_up(size_t v, size_t a) { return (v + a - 1) & ~(a - 1); }

extern "C" void kernel_launch(void* const* d_in, const int* in_sizes, int n_in,
                              void* d_out, int out_size, void* d_ws, size_t ws_size,
                              hipStream_t stream) {
    const float* x  = (const float*)d_in[0];
    const int*   ei = (const int*)d_in[1];
    const float* W1 = (const float*)d_in[2];
    const float* b1 = (const float*)d_in[3];
    const float* W2 = (const float*)d_in[4];
    const float* b2 = (const float*)d_in[5];
    float* out = (float*)d_out;

    const int N  = in_sizes[0] / D;   // 100000
    const int nE = in_sizes[1] / 2;   // 1600000
    const int* srcp = ei;
    const int* dstv = ei + nE;

    const int B = (N + NPB - 1) / NPB;      // 782
    const int C = (nE + CHUNK - 1) / CHUNK; // 196

    // --- workspace layout (bump allocator, 256B aligned) ---
    char* base_p = (char*)d_ws;
    size_t o = 0;
    int* counts = (int*)(base_p + o);  o = align_up(o + (size_t)C * B * 4, 256);
    int* btot   = (int*)(base_p + o);  o = align_up(o + (size_t)B * 4, 256);
    int* bbase  = (int*)(base_p + o);  o = align_up(o + (size_t)B * 4, 256);
    int* cursor = (int*)(base_p + o);  o = align_up(o + 4, 256);
    int* off    = (int*)(base_p + o);  o = align_up(o + (size_t)N * 4, 256);
    int* deg    = (int*)(base_p + o);  o = align_up(o + (size_t)N * 4, 256);
    float* dinv = (float*)(base_p + o); o = align_up(o + (size_t)N * 4, 256);
    int* entries1 = (int*)(base_p + o); o = align_up(o + (size_t)nE * 4, 256);
    __half* Hh  = (__half*)(base_p + o); o = align_up(o + (size_t)N * D * 2, 256);
    // region2: entries0 (nE*4) while building; Hh2 (N*D*2) after regroup
    size_t r2 = (size_t)nE * 4 > (size_t)N * D * 2 ? (size_t)nE * 4 : (size_t)N * D * 2;
    int* entries0 = (int*)(base_p + o);
    __half* Hh2   = (__half*)(base_p + o);
    o = align_up(o + r2, 256);
    size_t need_fused = o;             // ~34 MB
    // middle fallback (r9 path, A1 in d_out): entries0 aliases Hh region
    size_t need_mid = need_fused - align_up((size_t)N * D * 2, 256);

    int gb_n = (N + 255) / 256;
    int gb_g = (N + 63) / 64;
    int gb_e = (nE + 255) / 256;
    int gb_a = (N + 3) / 4;

    if (ws_size >= need_fused && B <= MAXB) {
        // ---- 6 dispatches ----
        hist_gemm1<<<C + gb_g, 256, 0, stream>>>(dstv, counts, cursor,
                                                 x, W1, Hh, nE, B, C, N);
        scan_alloc<<<(B + 3) / 4, 256, 0, stream>>>(counts, btot, bbase, cursor, B, C);
        scatter0_kernel<<<C, 256, 0, stream>>>(srcp, dstv, counts, bbase, entries0, nE, B);
        regroup_kernel<<<B, 256, 0, stream>>>(entries0, bbase, btot, off, deg, dinv, entries1, N);
        // entries0 dead; its memory becomes Hh2
        agg_gemm<<<gb_a, 256, 0, stream>>>(entries1, off, deg, dinv, Hh, b1, W2, Hh2, N);
        aggregate3<<<gb_a, 256, 0, stream>>>(entries1, off, deg, dinv, Hh2, b2, out, N);
    } else if (ws_size >= need_mid && B <= MAXB) {
        // ---- r9 path: 8 dispatches, A1(fp32) lives in d_out ----
        int* e0m = (int*)Hh;               // entries0 aliases Hh region
        __half* Hm = Hh;                   // Hh written after regroup
        hist_kernel<<<C, 256, 0, stream>>>(dstv, counts, cursor, nE, B);
        scan_alloc<<<(B + 3) / 4, 256, 0, stream>>>(counts, btot, bbase, cursor, B, C);
        scatter0_kernel<<<C, 256, 0, stream>>>(srcp, dstv, counts, bbase, e0m, nE, B);
        regroup_kernel<<<B, 256, 0, stream>>>(e0m, bbase, btot, off, deg, dinv, entries1, N);
        gemm_xwt_h<float><<<gb_g, 256, 0, stream>>>(x, W1, Hm, N);
        aggregate3<<<gb_a, 256, 0, stream>>>(entries1, off, deg, dinv, Hm, b1, out, N);
        gemm_xwt_h<float><<<gb_g, 256, 0, stream>>>(out, W2, Hm, N);
        aggregate3<<<gb_a, 256, 0, stream>>>(entries1, off, deg, dinv, Hm, b2, out, N);
    } else {
        // ---- ultimate fallback: round-1 atomic path ----
        size_t fo = 0;
        int* fdeg    = (int*)(base_p + fo);  fo = align_up(fo + (size_t)N * 4, 256);
        float* fdinv = (float*)(base_p + fo); fo = align_up(fo + (size_t)N * 4, 256);
        float* bufA  = (float*)(base_p + fo);
        hipMemsetAsync(fdeg, 0, (size_t)N * 4, stream);
        deg_kernel<<<gb_e, 256, 0, stream>>>(dstv, fdeg, nE);
        dinv_kernel<<<gb_n, 256, 0, stream>>>(fdeg, fdinv, N);
        int gb_i = (N * 16 + 255) / 256;
        int gb_e16 = (int)(((long long)nE * 16 + 255) / 256);
        gemm_xwt<<<gb_g, 256, 0, stream>>>(x, W1, bufA, N);
        init_out<<<gb_i, 256, 0, stream>>>(bufA, fdinv, b1, out, N);
        edge_scatter<<<gb_e16, 256, 0, stream>>>(srcp, dstv, fdinv, bufA, out, nE);
        gemm_xwt<<<gb_g, 256, 0, stream>>>(out, W2, bufA, N);
        init_out<<<gb_i, 256, 0, stream>>>(bufA, fdinv, b2, out, N);
        edge_scatter<<<gb_e16, 256, 0, stream>>>(srcp, dstv, fdinv, bufA, out, nE);
    }
}

// Round 11
// 287.255 us; speedup vs baseline: 1.0175x; 1.0175x over previous
//
#include <hip/hip_runtime.h>
#include <hip/hip_fp16.h>

// ---------------------------------------------------------------------------
// 2-layer GCN. Round 11: revert r10's agg_gemm fusion (LDS-pipe bound: 128
// ds_read/lane/node ~ 740 cyc/wave >> memory envelope; 93us vs 54+10 split).
// Keep: hist_gemm1 fat kernel, 4B entries, merged regroup, scan_alloc,
// fp16 A1 + separate tiled gemm2.
// Aggregate is AT the ~2.2 TB/s random-access traffic ceiling (r6/r8/r9:
// instruction changes flat, FETCH ~91MB ~ 8-XCD compulsory H re-fetch floor).
// Dispatches (7): hist_gemm1, scan_alloc, scatter0, regroup, agg1, gemm2, agg2.
// NEVER use cooperative grid.sync on this stack (r7: ~90us/sync).
// ---------------------------------------------------------------------------

#define D 64
#define NPB 128          // nodes per bucket (dst >> 7)
#define MAXB 784         // >= ceil(100000/128) = 782
#define CHUNK 8192       // edges per partition chunk

// === fatA: blocks [0,C) = per-chunk histogram; blocks [C,C+gbg) = gemm1 ====
__global__ __launch_bounds__(256) void hist_gemm1(const int* __restrict__ dst,
                                                  int* __restrict__ counts,
                                                  int* __restrict__ cursor,
                                                  const float* __restrict__ X,
                                                  const float* __restrict__ W1,
                                                  __half* __restrict__ H,
                                                  int nE, int B, int C, int N) {
    __shared__ __align__(16) char smem[34816];   // max(hist 3.1KB, gemm 34KB)
    const int t = threadIdx.x;
    if ((int)blockIdx.x < C) {
        // ---- histogram role ----
        int* hist = (int*)smem;
        if (blockIdx.x == 0 && t == 0) *cursor = 0;   // consumed by scan_alloc
        int c = blockIdx.x;
        for (int b = t; b < B; b += 256) hist[b] = 0;
        __syncthreads();
        int e0 = c * CHUNK;
#pragma unroll
        for (int i = 0; i < CHUNK / 256; ++i) {
            int e = e0 + i * 256 + t;
            if (e < nE) atomicAdd(&hist[dst[e] >> 7], 1);
        }
        __syncthreads();
        for (int b = t; b < B; b += 256) counts[c * B + b] = hist[b];
    } else {
        // ---- gemm1 role: H(fp16) = X(fp32) @ W1^T, 64x64 tile ----
        float* xt = (float*)smem;           // [64*68]
        float* wt = xt + 64 * 68;           // [64*68]
        const int i0 = ((int)blockIdx.x - C) * 64;
#pragma unroll
        for (int r = 0; r < 16; ++r) {
            int idx = r * 256 + t;
            int j = idx >> 6, k = idx & 63;
            wt[k * 68 + j] = W1[idx];
        }
#pragma unroll
        for (int r = 0; r < 16; ++r) {
            int idx = r * 256 + t;
            int i = idx >> 6, k = idx & 63;
            float v = 0.0f;
            if (i0 + i < N) v = X[(size_t)(i0 + i) * D + k];
            xt[k * 68 + i] = v;
        }
        __syncthreads();
        const int tn = (t & 15) * 4;
        const int tc = (t >> 4) * 4;
        float acc[4][4] = {};
#pragma unroll 8
        for (int k = 0; k < 64; ++k) {
            const float4 xa = *(const float4*)(xt + k * 68 + tn);
            const float4 wb = *(const float4*)(wt + k * 68 + tc);
            acc[0][0] += xa.x * wb.x; acc[0][1] += xa.x * wb.y; acc[0][2] += xa.x * wb.z; acc[0][3] += xa.x * wb.w;
            acc[1][0] += xa.y * wb.x; acc[1][1] += xa.y * wb.y; acc[1][2] += xa.y * wb.z; acc[1][3] += xa.y * wb.w;
            acc[2][0] += xa.z * wb.x; acc[2][1] += xa.z * wb.y; acc[2][2] += xa.z * wb.z; acc[2][3] += xa.z * wb.w;
            acc[3][0] += xa.w * wb.x; acc[3][1] += xa.w * wb.y; acc[3][2] += xa.w * wb.z; acc[3][3] += xa.w * wb.w;
        }
#pragma unroll
        for (int a = 0; a < 4; ++a) {
            int i = i0 + tn + a;
            if (i < N) {
                union { __half2 h2[2]; uint2 u2; } pk;
                pk.h2[0].x = __float2half_rn(acc[a][0]);
                pk.h2[0].y = __float2half_rn(acc[a][1]);
                pk.h2[1].x = __float2half_rn(acc[a][2]);
                pk.h2[1].y = __float2half_rn(acc[a][3]);
                *(uint2*)(&H[(size_t)i * D + tc]) = pk.u2;
            }
        }
    }
}

// --- S1: per-bucket chunk scan (in place) + region alloc via global cursor -
__global__ __launch_bounds__(256) void scan_alloc(int* __restrict__ counts,
                                                  int* __restrict__ btot,
                                                  int* __restrict__ bbase,
                                                  int* __restrict__ cursor,
                                                  int B, int C) {
    int b = blockIdx.x * 4 + (threadIdx.x >> 6);
    if (b >= B) return;
    int lane = threadIdx.x & 63;
    int running = 0;
    for (int c0 = 0; c0 < C; c0 += 64) {
        int c = c0 + lane;
        int v = (c < C) ? counts[c * B + b] : 0;
        int x = v;
#pragma unroll
        for (int s = 1; s < 64; s <<= 1) {
            int u = __shfl_up(x, s);
            if (lane >= s) x += u;
        }
        if (c < C) counts[c * B + b] = running + x - v;
        running += __shfl(x, 63);
    }
    if (lane == 0) {
        int base = atomicAdd(cursor, running);   // order-free region alloc
        bbase[b] = base;
        btot[b]  = running;
    }
}

// --- A3: scatter 4B entries (src | dloc<<17) via LDS cursors ---------------
__global__ __launch_bounds__(256) void scatter0_kernel(const int* __restrict__ src,
                                                       const int* __restrict__ dst,
                                                       const int* __restrict__ base,
                                                       const int* __restrict__ bbase,
                                                       int* __restrict__ entries0,
                                                       int nE, int B) {
    __shared__ int cur[MAXB];
    int c = blockIdx.x;
    for (int b = threadIdx.x; b < B; b += 256) cur[b] = base[c * B + b] + bbase[b];
    __syncthreads();
    int e0 = c * CHUNK;
#pragma unroll
    for (int i = 0; i < CHUNK / 256; ++i) {
        int e = e0 + i * 256 + threadIdx.x;
        if (e < nE) {
            int s = src[e], d = dst[e];
            int pos = atomicAdd(&cur[d >> 7], 1);
            entries0[pos] = s | ((d & (NPB - 1)) << 17);
        }
    }
}

// --- A4: merged regroup: count+scan -> off/deg/dinv, node-sorted src -------
__global__ __launch_bounds__(256) void regroup_kernel(const int* __restrict__ entries0,
                                                      const int* __restrict__ bbase,
                                                      const int* __restrict__ btot,
                                                      int* __restrict__ off,
                                                      int* __restrict__ deg,
                                                      float* __restrict__ dinv,
                                                      int* __restrict__ entries1, int N) {
    __shared__ int cnt[NPB];
    __shared__ int scn[NPB];
    __shared__ int cur[NPB];
    int b = blockIdx.x;
    int t = threadIdx.x;
    if (t < NPB) cnt[t] = 0;
    __syncthreads();
    int s0 = bbase[b], s1 = s0 + btot[b];
    for (int p = s0 + t; p < s1; p += 256)
        atomicAdd(&cnt[(entries0[p] >> 17) & (NPB - 1)], 1);
    __syncthreads();
    if (t < NPB) scn[t] = cnt[t];
    __syncthreads();
    for (int s = 1; s < NPB; s <<= 1) {
        int u = 0;
        if (t < NPB && t >= s) u = scn[t - s];
        __syncthreads();
        if (t < NPB) scn[t] += u;
        __syncthreads();
    }
    if (t < NPB) {
        int node = b * NPB + t;
        int c = cnt[t];
        int o = s0 + scn[t] - c;
        cur[t] = o;
        if (node < N) {
            off[node]  = o;
            deg[node]  = c;
            dinv[node] = rsqrtf((float)c + 1.0f);
        }
    }
    __syncthreads();
    for (int p = s0 + t; p < s1; p += 256) {
        int e = entries0[p];
        int pos = atomicAdd(&cur[(e >> 17) & (NPB - 1)], 1);
        entries1[pos] = e & 0x1FFFF;
    }
}

// --- aggregate3: one wave per node, dual-edge half2, 4B src entries --------
template <typename OutT>
__global__ __launch_bounds__(256) void aggregate3(const int* __restrict__ csr,
                                                  const int* __restrict__ off,
                                                  const int* __restrict__ deg,
                                                  const float* __restrict__ dinv,
                                                  const __half* __restrict__ H,
                                                  const float* __restrict__ bias,
                                                  OutT* __restrict__ out, int N) {
    int node = blockIdx.x * 4 + (threadIdx.x >> 6);
    if (node >= N) return;
    int lane = threadIdx.x & 63;
    int p2 = lane & 31;
    int h  = lane >> 5;
    const __half2* H2 = (const __half2*)H;
    float dd = dinv[node];
    float2 acc = make_float2(0.0f, 0.0f);
    int beg = off[node];
    int end = beg + deg[node];
    int p = beg;
    for (; p + 8 <= end; p += 8) {
        int s0v = csr[p + 0 + h], s1v = csr[p + 2 + h];
        int s2v = csr[p + 4 + h], s3v = csr[p + 6 + h];
        __half2 g0 = H2[(size_t)s0v * 32 + p2];
        __half2 g1 = H2[(size_t)s1v * 32 + p2];
        __half2 g2 = H2[(size_t)s2v * 32 + p2];
        __half2 g3 = H2[(size_t)s3v * 32 + p2];
        float c0 = dinv[s0v] * dd, c1 = dinv[s1v] * dd;
        float c2 = dinv[s2v] * dd, c3 = dinv[s3v] * dd;
        float2 f0 = __half22float2(g0), f1 = __half22float2(g1);
        float2 f2 = __half22float2(g2), f3 = __half22float2(g3);
        acc.x += f0.x * c0; acc.y += f0.y * c0;
        acc.x += f1.x * c1; acc.y += f1.y * c1;
        acc.x += f2.x * c2; acc.y += f2.y * c2;
        acc.x += f3.x * c3; acc.y += f3.y * c3;
    }
    for (; p + 2 <= end; p += 2) {
        int s0v = csr[p + h];
        __half2 g0 = H2[(size_t)s0v * 32 + p2];
        float c0 = dinv[s0v] * dd;
        float2 f0 = __half22float2(g0);
        acc.x += f0.x * c0; acc.y += f0.y * c0;
    }
    if (p < end && h == 0) {
        int s0v = csr[p];
        __half2 g0 = H2[(size_t)s0v * 32 + p2];
        float c0 = dinv[s0v] * dd;
        float2 f0 = __half22float2(g0);
        acc.x += f0.x * c0; acc.y += f0.y * c0;
    }
    acc.x += __shfl_xor(acc.x, 32);
    acc.y += __shfl_xor(acc.y, 32);
    if (h == 0) {
        float s = dd * dd;
        float2 hs = __half22float2(H2[(size_t)node * 32 + p2]);
        float2 bv = ((const float2*)bias)[p2];
        float2 o;
        o.x = acc.x + bv.x + hs.x * s;
        o.y = acc.y + bv.y + hs.y * s;
        if constexpr (sizeof(OutT) == 2) {
            ((__half2*)(out + (size_t)node * D))[p2] = __float22half2_rn(o);
        } else {
            ((float2*)(out + (size_t)node * D))[p2] = o;
        }
    }
}

// --- H(fp16) = X @ W^T : 64x64 block tile, 4x4 register tile ---------------
template <typename InT>
__global__ __launch_bounds__(256) void gemm_xwt_h(const InT* __restrict__ X,
                                                  const float* __restrict__ W,
                                                  __half* __restrict__ H, int N) {
    __shared__ float xt[64 * 68];
    __shared__ float wt[64 * 68];
    const int t = threadIdx.x;
    const int i0 = blockIdx.x * 64;
#pragma unroll
    for (int r = 0; r < 16; ++r) {
        int idx = r * 256 + t;
        int j = idx >> 6, k = idx & 63;
        wt[k * 68 + j] = W[idx];
    }
#pragma unroll
    for (int r = 0; r < 16; ++r) {
        int idx = r * 256 + t;
        int i = idx >> 6, k = idx & 63;
        float v = 0.0f;
        if (i0 + i < N) {
            if constexpr (sizeof(InT) == 2)
                v = __half2float(((const __half*)X)[(size_t)(i0 + i) * D + k]);
            else
                v = ((const float*)X)[(size_t)(i0 + i) * D + k];
        }
        xt[k * 68 + i] = v;
    }
    __syncthreads();
    const int tn = (t & 15) * 4;
    const int tc = (t >> 4) * 4;
    float acc[4][4] = {};
#pragma unroll 8
    for (int k = 0; k < 64; ++k) {
        const float4 xa = *(const float4*)(xt + k * 68 + tn);
        const float4 wb = *(const float4*)(wt + k * 68 + tc);
        acc[0][0] += xa.x * wb.x; acc[0][1] += xa.x * wb.y; acc[0][2] += xa.x * wb.z; acc[0][3] += xa.x * wb.w;
        acc[1][0] += xa.y * wb.x; acc[1][1] += xa.y * wb.y; acc[1][2] += xa.y * wb.z; acc[1][3] += xa.y * wb.w;
        acc[2][0] += xa.z * wb.x; acc[2][1] += xa.z * wb.y; acc[2][2] += xa.z * wb.z; acc[2][3] += xa.z * wb.w;
        acc[3][0] += xa.w * wb.x; acc[3][1] += xa.w * wb.y; acc[3][2] += xa.w * wb.z; acc[3][3] += xa.w * wb.w;
    }
#pragma unroll
    for (int a = 0; a < 4; ++a) {
        int i = i0 + tn + a;
        if (i < N) {
            union { __half2 h2[2]; uint2 u2; } pk;
            pk.h2[0].x = __float2half_rn(acc[a][0]);
            pk.h2[0].y = __float2half_rn(acc[a][1]);
            pk.h2[1].x = __float2half_rn(acc[a][2]);
            pk.h2[1].y = __float2half_rn(acc[a][3]);
            *(uint2*)(&H[(size_t)i * D + tc]) = pk.u2;
        }
    }
}

// --- standalone hist (middle fallback path) --------------------------------
__global__ __launch_bounds__(256) void hist_kernel(const int* __restrict__ dst,
                                                   int* __restrict__ counts,
                                                   int* __restrict__ cursor,
                                                   int nE, int B) {
    __shared__ int hist[MAXB];
    if (blockIdx.x == 0 && threadIdx.x == 0) *cursor = 0;
    int c = blockIdx.x;
    for (int b = threadIdx.x; b < B; b += 256) hist[b] = 0;
    __syncthreads();
    int e0 = c * CHUNK;
#pragma unroll
    for (int i = 0; i < CHUNK / 256; ++i) {
        int e = e0 + i * 256 + threadIdx.x;
        if (e < nE) atomicAdd(&hist[dst[e] >> 7], 1);
    }
    __syncthreads();
    for (int b = threadIdx.x; b < B; b += 256) counts[c * B + b] = hist[b];
}

// --- ultimate fallback (round-1 fp32 atomic path) kernels ------------------
__global__ __launch_bounds__(256) void deg_kernel(const int* __restrict__ dst,
                                                  int* __restrict__ deg, int nE) {
    int e = blockIdx.x * 256 + threadIdx.x;
    if (e < nE) atomicAdd(&deg[dst[e]], 1);
}

__global__ __launch_bounds__(256) void dinv_kernel(const int* __restrict__ deg,
                                                   float* __restrict__ dinv, int N) {
    int i = blockIdx.x * 256 + threadIdx.x;
    if (i < N) dinv[i] = rsqrtf((float)deg[i] + 1.0f);
}

__global__ __launch_bounds__(256) void gemm_xwt(const float* __restrict__ X,
                                                const float* __restrict__ W,
                                                float* __restrict__ H, int N) {
    __shared__ float xt[64 * 68];
    __shared__ float wt[64 * 68];
    const int t = threadIdx.x;
    const int i0 = blockIdx.x * 64;
#pragma unroll
    for (int r = 0; r < 16; ++r) {
        int idx = r * 256 + t;
        int j = idx >> 6, k = idx & 63;
        wt[k * 68 + j] = W[idx];
    }
#pragma unroll
    for (int r = 0; r < 16; ++r) {
        int idx = r * 256 + t;
        int i = idx >> 6, k = idx & 63;
        float v = 0.0f;
        if (i0 + i < N) v = X[(size_t)(i0 + i) * D + k];
        xt[k * 68 + i] = v;
    }
    __syncthreads();
    const int tn = (t & 15) * 4;
    const int tc = (t >> 4) * 4;
    float acc[4][4] = {};
#pragma unroll 8
    for (int k = 0; k < 64; ++k) {
        const float4 xa = *(const float4*)(xt + k * 68 + tn);
        const float4 wb = *(const float4*)(wt + k * 68 + tc);
        acc[0][0] += xa.x * wb.x; acc[0][1] += xa.x * wb.y; acc[0][2] += xa.x * wb.z; acc[0][3] += xa.x * wb.w;
        acc[1][0] += xa.y * wb.x; acc[1][1] += xa.y * wb.y; acc[1][2] += xa.y * wb.z; acc[1][3] += xa.y * wb.w;
        acc[2][0] += xa.z * wb.x; acc[2][1] += xa.z * wb.y; acc[2][2] += xa.z * wb.z; acc[2][3] += xa.z * wb.w;
        acc[3][0] += xa.w * wb.x; acc[3][1] += xa.w * wb.y; acc[3][2] += xa.w * wb.z; acc[3][3] += xa.w * wb.w;
    }
#pragma unroll
    for (int a = 0; a < 4; ++a) {
        int i = i0 + tn + a;
        if (i < N) {
            float4 o = make_float4(acc[a][0], acc[a][1], acc[a][2], acc[a][3]);
            *(float4*)(H + (size_t)i * D + tc) = o;
        }
    }
}

__global__ __launch_bounds__(256) void init_out(const float* __restrict__ H,
                                                const float* __restrict__ dinv,
                                                const float* __restrict__ b,
                                                float* __restrict__ out, int N) {
    int idx4 = blockIdx.x * 256 + threadIdx.x;
    if (idx4 >= N * 16) return;
    int i = idx4 >> 4;
    int jc = idx4 & 15;
    float di = dinv[i];
    float s = di * di;
    float4 h4 = ((const float4*)H)[idx4];
    float4 b4 = ((const float4*)b)[jc];
    ((float4*)out)[idx4] = make_float4(b4.x + h4.x * s, b4.y + h4.y * s,
                                       b4.z + h4.z * s, b4.w + h4.w * s);
}

__global__ __launch_bounds__(256) void edge_scatter(const int* __restrict__ src,
                                                    const int* __restrict__ dst,
                                                    const float* __restrict__ dinv,
                                                    const float* __restrict__ H,
                                                    float* __restrict__ out, int nE) {
    int tid = blockIdx.x * 256 + threadIdx.x;
    int e = tid >> 4;
    if (e >= nE) return;
    int l = tid & 15;
    int s = src[e];
    int d = dst[e];
    float c = dinv[s] * dinv[d];
    float4 v = ((const float4*)H)[s * 16 + l];
    float* o = out + (size_t)d * D + l * 4;
    unsafeAtomicAdd(o + 0, v.x * c);
    unsafeAtomicAdd(o + 1, v.y * c);
    unsafeAtomicAdd(o + 2, v.z * c);
    unsafeAtomicAdd(o + 3, v.w * c);
}

static inline size_t align_up(size_t v, size_t a) { return (v + a - 1) & ~(a - 1); }

extern "C" void kernel_launch(void* const* d_in, const int* in_sizes, int n_in,
                              void* d_out, int out_size, void* d_ws, size_t ws_size,
                              hipStream_t stream) {
    const float* x  = (const float*)d_in[0];
    const int*   ei = (const int*)d_in[1];
    const float* W1 = (const float*)d_in[2];
    const float* b1 = (const float*)d_in[3];
    const float* W2 = (const float*)d_in[4];
    const float* b2 = (const float*)d_in[5];
    float* out = (float*)d_out;

    const int N  = in_sizes[0] / D;   // 100000
    const int nE = in_sizes[1] / 2;   // 1600000
    const int* srcp = ei;
    const int* dstv = ei + nE;

    const int B = (N + NPB - 1) / NPB;      // 782
    const int C = (nE + CHUNK - 1) / CHUNK; // 196

    // --- workspace layout (bump allocator, 256B aligned) ---
    char* base_p = (char*)d_ws;
    size_t o = 0;
    int* counts = (int*)(base_p + o);  o = align_up(o + (size_t)C * B * 4, 256);
    int* btot   = (int*)(base_p + o);  o = align_up(o + (size_t)B * 4, 256);
    int* bbase  = (int*)(base_p + o);  o = align_up(o + (size_t)B * 4, 256);
    int* cursor = (int*)(base_p + o);  o = align_up(o + 4, 256);
    int* off    = (int*)(base_p + o);  o = align_up(o + (size_t)N * 4, 256);
    int* deg    = (int*)(base_p + o);  o = align_up(o + (size_t)N * 4, 256);
    float* dinv = (float*)(base_p + o); o = align_up(o + (size_t)N * 4, 256);
    int* entries1 = (int*)(base_p + o); o = align_up(o + (size_t)nE * 4, 256);
    __half* Hh  = (__half*)(base_p + o); o = align_up(o + (size_t)N * D * 2, 256);
    // region2: entries0 (nE*4) while building; A1h (N*D*2) after agg1
    size_t r2 = (size_t)nE * 4 > (size_t)N * D * 2 ? (size_t)nE * 4 : (size_t)N * D * 2;
    int* entries0 = (int*)(base_p + o);
    __half* A1h   = (__half*)(base_p + o);
    o = align_up(o + r2, 256);
    size_t need_fused = o;             // ~34 MB
    size_t need_mid = need_fused - align_up((size_t)N * D * 2, 256);

    int gb_n = (N + 255) / 256;
    int gb_g = (N + 63) / 64;
    int gb_e = (nE + 255) / 256;
    int gb_a = (N + 3) / 4;

    if (ws_size >= need_fused && B <= MAXB) {
        // ---- 7 dispatches ----
        hist_gemm1<<<C + gb_g, 256, 0, stream>>>(dstv, counts, cursor,
                                                 x, W1, Hh, nE, B, C, N);
        scan_alloc<<<(B + 3) / 4, 256, 0, stream>>>(counts, btot, bbase, cursor, B, C);
        scatter0_kernel<<<C, 256, 0, stream>>>(srcp, dstv, counts, bbase, entries0, nE, B);
        regroup_kernel<<<B, 256, 0, stream>>>(entries0, bbase, btot, off, deg, dinv, entries1, N);
        // entries0 dead; region becomes A1h
        aggregate3<__half><<<gb_a, 256, 0, stream>>>(entries1, off, deg, dinv, Hh, b1, A1h, N);
        // H1 dead; gemm2 overwrites Hh with layer-2 features
        gemm_xwt_h<__half><<<gb_g, 256, 0, stream>>>(A1h, W2, Hh, N);
        aggregate3<float><<<gb_a, 256, 0, stream>>>(entries1, off, deg, dinv, Hh, b2, out, N);
    } else if (ws_size >= need_mid && B <= MAXB) {
        // ---- r9-style path: A1(fp32) lives in d_out ----
        int* e0m = (int*)Hh;               // entries0 aliases Hh region
        __half* Hm = Hh;
        hist_kernel<<<C, 256, 0, stream>>>(dstv, counts, cursor, nE, B);
        scan_alloc<<<(B + 3) / 4, 256, 0, stream>>>(counts, btot, bbase, cursor, B, C);
        scatter0_kernel<<<C, 256, 0, stream>>>(srcp, dstv, counts, bbase, e0m, nE, B);
        regroup_kernel<<<B, 256, 0, stream>>>(e0m, bbase, btot, off, deg, dinv, entries1, N);
        gemm_xwt_h<float><<<gb_g, 256, 0, stream>>>(x, W1, Hm, N);
        aggregate3<float><<<gb_a, 256, 0, stream>>>(entries1, off, deg, dinv, Hm, b1, out, N);
        gemm_xwt_h<float><<<gb_g, 256, 0, stream>>>(out, W2, Hm, N);
        aggregate3<float><<<gb_a, 256, 0, stream>>>(entries1, off, deg, dinv, Hm, b2, out, N);
    } else {
        // ---- ultimate fallback: round-1 atomic path ----
        size_t fo = 0;
        int* fdeg    = (int*)(base_p + fo);  fo = align_up(fo + (size_t)N * 4, 256);
        float* fdinv = (float*)(base_p + fo); fo = align_up(fo + (size_t)N * 4, 256);
        float* bufA  = (float*)(base_p + fo);
        hipMemsetAsync(fdeg, 0, (size_t)N * 4, stream);
        deg_kernel<<<gb_e, 256, 0, stream>>>(dstv, fdeg, nE);
        dinv_kernel<<<gb_n, 256, 0, stream>>>(fdeg, fdinv, N);
        int gb_i = (N * 16 + 255) / 256;
        int gb_e16 = (int)(((long long)nE * 16 + 255) / 256);
        gemm_xwt<<<gb_g, 256, 0, stream>>>(x, W1, bufA, N);
        init_out<<<gb_i, 256, 0, stream>>>(bufA, fdinv, b1, out, N);
        edge_scatter<<<gb_e16, 256, 0, stream>>>(srcp, dstv, fdinv, bufA, out, nE);
        gemm_xwt<<<gb_g, 256, 0, stream>>>(out, W2, bufA, N);
        init_out<<<gb_i, 256, 0, stream>>>(bufA, fdinv, b2, out, N);
        edge_scatter<<<gb_e16, 256, 0, stream>>>(srcp, dstv, fdinv, bufA, out, nE);
    }
}